// Round 1
// baseline (158.021 us; speedup 1.0000x reference)
//
#include <hip/hip_runtime.h>

// AdderNet conv: out[n,co,i,j] = -sum_{ci,kh,kw} |x[n,ci,i+kh,j+kw] - W[co,ci,kh,kw]|
// x: (16,5,512,512) fp32, W: (5,5,3,3) fp32, out: (16,5,510,510) fp32

#define KK 3
#define NB 16
#define CI 5
#define CO 5
#define H 512
#define WD 512
#define HO 510
#define WO 510
#define TW 64   // tile width  (columns, = lanes)
#define TH 16   // tile height (4 ty groups x 4 rows/thread)

__global__ __launch_bounds__(256)
void adder2d_kernel(const float* __restrict__ x,
                    const float* __restrict__ Wg,
                    float* __restrict__ out) {
    const int tx = threadIdx.x & 63;     // column within tile
    const int ty = threadIdx.x >> 6;     // 0..3 row group
    const int j0 = blockIdx.x * TW;
    const int i0 = blockIdx.y * TH;
    const int n  = blockIdx.z;

    const int j     = j0 + tx;           // output column
    const int ibase = i0 + ty * 4;       // first of this thread's 4 output rows

    // Register window: 5 ci x 6 rows x 3 cols (covers 4 output rows of 3x3 taps)
    float xv[CI][6][KK];
    const float* xn = x + (size_t)n * CI * H * WD;
    #pragma unroll
    for (int ci = 0; ci < CI; ++ci) {
        #pragma unroll
        for (int r = 0; r < 6; ++r) {
            int gi = ibase + r;
            gi = gi < H ? gi : H - 1;            // clamp (values unused for OOB rows)
            const float* rowp = xn + (size_t)ci * H * WD + (size_t)gi * WD;
            #pragma unroll
            for (int k = 0; k < KK; ++k) {
                int gj = j + k;
                gj = gj < WD ? gj : WD - 1;      // clamp (values unused for OOB cols)
                xv[ci][r][k] = rowp[gj];
            }
        }
    }

    const bool jvalid = (j < WO);
    float* outn = out + (size_t)n * CO * HO * WO;

    // co loop kept rolled: only 45 uniform W values live per iteration -> s_loads,
    // scalar pipe runs parallel to the 360 VALU ops of the iteration body.
    #pragma unroll 1
    for (int co = 0; co < CO; ++co) {
        float acc0 = 0.f, acc1 = 0.f, acc2 = 0.f, acc3 = 0.f;
        const float* wp = Wg + co * (CI * KK * KK);
        #pragma unroll
        for (int ci = 0; ci < CI; ++ci) {
            #pragma unroll
            for (int kh = 0; kh < KK; ++kh) {
                #pragma unroll
                for (int kw = 0; kw < KK; ++kw) {
                    const float w = wp[ci * 9 + kh * 3 + kw];
                    acc0 += fabsf(xv[ci][kh + 0][kw] - w);
                    acc1 += fabsf(xv[ci][kh + 1][kw] - w);
                    acc2 += fabsf(xv[ci][kh + 2][kw] - w);
                    acc3 += fabsf(xv[ci][kh + 3][kw] - w);
                }
            }
        }
        if (jvalid) {
            float accs[4] = {acc0, acc1, acc2, acc3};
            float* outc = outn + (size_t)co * HO * WO;
            #pragma unroll
            for (int rr = 0; rr < 4; ++rr) {
                const int i = ibase + rr;
                if (i < HO) outc[(size_t)i * WO + j] = -accs[rr];
            }
        }
    }
}

extern "C" void kernel_launch(void* const* d_in, const int* in_sizes, int n_in,
                              void* d_out, int out_size, void* d_ws, size_t ws_size,
                              hipStream_t stream) {
    const float* x  = (const float*)d_in[0];
    const float* Wg = (const float*)d_in[1];
    float* out      = (float*)d_out;

    dim3 grid((WO + TW - 1) / TW,   // 8
              (HO + TH - 1) / TH,   // 32
              NB);                  // 16
    dim3 block(256);
    adder2d_kernel<<<grid, block, 0, stream>>>(x, Wg, out);
}